// Round 1
// baseline (379.454 us; speedup 1.0000x reference)
//
#include <hip/hip_runtime.h>
#include <math.h>

#define LOG2E 1.4426950408889634f

typedef __attribute__((ext_vector_type(8))) __bf16 bf16x8_t;
typedef __attribute__((ext_vector_type(8))) short short8_t;
typedef __attribute__((ext_vector_type(4))) float f32x4;

static __device__ __forceinline__ short f2bf(float f){
    unsigned u = __builtin_bit_cast(unsigned, f);
    unsigned r = (u + 0x7fffu + ((u >> 16) & 1u)) >> 16;
    return (short)r;
}

static __device__ __forceinline__ f32x4 mfma16(short8_t a, short8_t b, f32x4 c){
    return __builtin_amdgcn_mfma_f32_16x16x32_bf16(
        __builtin_bit_cast(bf16x8_t, a), __builtin_bit_cast(bf16x8_t, b), c, 0, 0, 0);
}

// ---------- K1: weights -> bf16, transposed to [mat][d][c] ----------
__global__ __launch_bounds__(256) void prep_w(const float* __restrict__ w0,
    const float* __restrict__ w1, const float* __restrict__ w2,
    const float* __restrict__ w3, short* __restrict__ wT)
{
    int t = blockIdx.x * 256 + threadIdx.x;        // 4 * 65536 total
    int mat = t >> 16, r = t & 65535, d = r >> 8, c = r & 255;
    const float* src = mat == 0 ? w0 : mat == 1 ? w1 : mat == 2 ? w2 : w3;
    wT[t] = f2bf(src[c * 256 + d]);
}

// ---------- K2: per-pixel GroupNorm (G=32, 8 ch/group), write hn (B, m~=w*64+h, C) bf16 ----------
__global__ __launch_bounds__(256) void gn_kernel(const float* __restrict__ x,
    const float* __restrict__ gnw, const float* __restrict__ gnb,
    short* __restrict__ hn)
{
    int flat = blockIdx.x * 256 + threadIdx.x;     // b*(32*4096) + g*4096 + n
    int n = flat & 4095, g = (flat >> 12) & 31, b = flat >> 17;
    const float* xp = x + (size_t)(b * 256 + g * 8) * 4096 + n;
    float v[8], s = 0.f, s2 = 0.f;
    #pragma unroll
    for (int k = 0; k < 8; k++){ float t = xp[(size_t)k * 4096]; v[k] = t; s += t; s2 += t * t; }
    float mean = s * 0.125f;
    float var  = s2 * 0.125f - mean * mean;
    float inv  = rsqrtf(var + 1e-6f);
    int h = n >> 6, w = n & 63, m = w * 64 + h;    // spatial transpose: column-major index
    short o[8];
    #pragma unroll
    for (int k = 0; k < 8; k++)
        o[k] = f2bf((v[k] - mean) * inv * gnw[g * 8 + k] + gnb[g * 8 + k]);
    *(short8_t*)(hn + (size_t)(b * 4096 + m) * 256 + g * 8) = *(short8_t*)o;
}

// ---------- K3: QKV GEMM. A = hn [16384 x 256], B = wT[mat] (d-major). ----------
// Q,K out (B, m~, C) bf16; V out transposed (B, C, m~) bf16 via LDS transpose.
__global__ __launch_bounds__(256) void qkv_gemm(const short* __restrict__ hn,
    const short* __restrict__ wT, const float* __restrict__ bq,
    const float* __restrict__ bk, const float* __restrict__ bv,
    short* __restrict__ Q, short* __restrict__ K, short* __restrict__ Vt)
{
    __shared__ short As[64 * 72];   // pad 64->72 shorts: row stride 144B, bank-rotated
    __shared__ short Bs[64 * 72];
    __shared__ float CT[64 * 65];   // f32 transpose staging (V only)

    const int tid = threadIdx.x;
    const int m0 = blockIdx.x * 64;
    const int by = blockIdx.y;
    const int mat = by >> 2;                 // 0=Q 1=K 2=V
    const int d0 = (by & 3) * 64;
    const short* w = wT + mat * 65536;
    const float* bias = mat == 0 ? bq : mat == 1 ? bk : bv;

    const int wv = tid >> 6, lane = tid & 63;
    const int wrow = (wv >> 1) * 32, wcol = (wv & 1) * 32;
    const int lrow = lane & 15, lq = lane >> 4;

    f32x4 acc[2][2] = {};

    for (int k0 = 0; k0 < 256; k0 += 64){
        __syncthreads();
        #pragma unroll
        for (int i = 0; i < 2; i++){
            int idx = tid + i * 256, r = idx >> 3, c = (idx & 7) * 8;
            *(short8_t*)&As[r * 72 + c] = *(const short8_t*)(hn + (size_t)(m0 + r) * 256 + k0 + c);
            *(short8_t*)&Bs[r * 72 + c] = *(const short8_t*)(w  + (size_t)(d0 + r) * 256 + k0 + c);
        }
        __syncthreads();
        #pragma unroll
        for (int kk = 0; kk < 2; kk++){
            int off = kk * 32 + lq * 8;
            short8_t a0  = *(short8_t*)&As[(wrow + lrow) * 72 + off];
            short8_t a1  = *(short8_t*)&As[(wrow + 16 + lrow) * 72 + off];
            short8_t b0v = *(short8_t*)&Bs[(wcol + lrow) * 72 + off];
            short8_t b1v = *(short8_t*)&Bs[(wcol + 16 + lrow) * 72 + off];
            acc[0][0] = mfma16(a0, b0v, acc[0][0]);
            acc[0][1] = mfma16(a0, b1v, acc[0][1]);
            acc[1][0] = mfma16(a1, b0v, acc[1][0]);
            acc[1][1] = mfma16(a1, b1v, acc[1][1]);
        }
    }

    if (mat < 2){
        short* out = (mat == 0) ? Q : K;
        #pragma unroll
        for (int i = 0; i < 2; i++)
          #pragma unroll
          for (int j = 0; j < 2; j++)
            #pragma unroll
            for (int r = 0; r < 4; r++){
                int row = wrow + i * 16 + lq * 4 + r;
                int col = wcol + j * 16 + lrow;
                out[(size_t)(m0 + row) * 256 + d0 + col] = f2bf(acc[i][j][r] + bias[d0 + col]);
            }
    } else {
        #pragma unroll
        for (int i = 0; i < 2; i++)
          #pragma unroll
          for (int j = 0; j < 2; j++)
            #pragma unroll
            for (int r = 0; r < 4; r++){
                int row = wrow + i * 16 + lq * 4 + r;
                int col = wcol + j * 16 + lrow;
                CT[col * 65 + row] = acc[i][j][r] + bias[d0 + col];
            }
        __syncthreads();
        int b = m0 >> 12, mloc = m0 & 4095;
        int dr = tid >> 2, wc = (tid & 3) * 16;
        short tmp[16];
        #pragma unroll
        for (int j = 0; j < 16; j++) tmp[j] = f2bf(CT[dr * 65 + wc + j]);
        short* dst = Vt + (size_t)(b * 256 + d0 + dr) * 4096 + mloc + wc;
        *(short8_t*)dst = *(short8_t*)tmp;
        *(short8_t*)(dst + 8) = *(short8_t*)(tmp + 8);
    }
}

// ---------- K4: flash attention, block = (b, w, h-half). No masking needed. ----------
__global__ __launch_bounds__(256) void attn_kernel(const short* __restrict__ Q,
    const short* __restrict__ K, const short* __restrict__ Vt,
    short* __restrict__ hb)
{
    __shared__ short KVs[18432];     // union: K tile [64][264] (16896) / Vt tile [256][72] (18432)
    __shared__ float Sls[32 * 66];   // scores, padded stride
    __shared__ short Pls[32 * 72];   // P bf16, padded stride (144B rows)
    __shared__ float mst[32], lst[32], alph[32];
    __shared__ float pmax[256], psum[256];

    const int tid = threadIdx.x, lane = tid & 63, wv = tid >> 6;
    const int lrow = lane & 15, lq = lane >> 4;
    const int b = blockIdx.y;
    const int w = 63 - (blockIdx.x >> 1);   // long blocks dispatched first
    const int hh = blockIdx.x & 1;
    const int q0 = w * 64 + hh * 32;        // m~ base of the 32 queries

    // Q fragments held in registers: 32 rows x 256 k
    short8_t qf[2][8];
    {
        const short* qp = Q + ((size_t)b * 4096 + q0) * 256;
        #pragma unroll
        for (int rg = 0; rg < 2; rg++)
            #pragma unroll
            for (int ks = 0; ks < 8; ks++)
                qf[rg][ks] = *(const short8_t*)(qp + (size_t)(rg * 16 + lrow) * 256 + ks * 32 + lq * 8);
    }
    f32x4 oacc[2][4] = {};
    if (tid < 32){ mst[tid] = -INFINITY; lst[tid] = 0.f; }

    const int nkb = w + 1;
    for (int kb = 0; kb < nkb; kb++){
        __syncthreads();
        // stage K tile [64 keys][256 ch] (padded stride 264)
        {
            const short* src = K + ((size_t)b * 4096 + kb * 64) * 256;
            #pragma unroll
            for (int i = 0; i < 8; i++){
                int idx = tid + i * 256, r = idx >> 5, c = (idx & 31) * 8;
                *(short8_t*)&KVs[r * 264 + c] = *(const short8_t*)(src + (size_t)r * 256 + c);
            }
        }
        __syncthreads();
        // S = Q K^T ; wave wv owns keys [wv*16, wv*16+16)
        {
            f32x4 s0 = {}, s1 = {};
            #pragma unroll
            for (int ks = 0; ks < 8; ks++){
                short8_t bf = *(short8_t*)&KVs[(wv * 16 + lrow) * 264 + ks * 32 + lq * 8];
                s0 = mfma16(qf[0][ks], bf, s0);
                s1 = mfma16(qf[1][ks], bf, s1);
            }
            #pragma unroll
            for (int r = 0; r < 4; r++){
                Sls[(lq * 4 + r) * 66 + wv * 16 + lrow]        = s0[r] * 0.0625f;
                Sls[(16 + lq * 4 + r) * 66 + wv * 16 + lrow]   = s1[r] * 0.0625f;
            }
        }
        __syncthreads();
        // softmax phase1: per-(row, 8-col-chunk) partial max
        {
            int row = tid & 31, ch = tid >> 5;
            const float* sp = &Sls[row * 66 + ch * 8];
            float m = sp[0];
            #pragma unroll
            for (int j = 1; j < 8; j++) m = fmaxf(m, sp[j]);
            pmax[row * 8 + ch] = m;
        }
        __syncthreads();
        // phase2: new running max, alpha
        if (tid < 32){
            float mo = mst[tid], mn = mo;
            #pragma unroll
            for (int c = 0; c < 8; c++) mn = fmaxf(mn, pmax[tid * 8 + c]);
            float al = exp2f((mo - mn) * LOG2E);
            alph[tid] = al; mst[tid] = mn; lst[tid] *= al;
        }
        __syncthreads();
        // phase3: P = exp(S - m), partial sums; rescale O accumulators by alpha
        {
            int row = tid & 31, ch = tid >> 5;
            float mn = mst[row];
            const float* sp = &Sls[row * 66 + ch * 8];
            short pv[8]; float sum = 0.f;
            #pragma unroll
            for (int j = 0; j < 8; j++){
                float p = exp2f((sp[j] - mn) * LOG2E);
                sum += p; pv[j] = f2bf(p);
            }
            *(short8_t*)&Pls[row * 72 + ch * 8] = *(short8_t*)pv;
            psum[row * 8 + ch] = sum;
        }
        #pragma unroll
        for (int rg = 0; rg < 2; rg++)
            #pragma unroll
            for (int r = 0; r < 4; r++){
                float al = alph[rg * 16 + lq * 4 + r];
                #pragma unroll
                for (int nt = 0; nt < 4; nt++) oacc[rg][nt][r] *= al;
            }
        __syncthreads();
        // phase4 (l update) + stage Vt tile [256 ch][64 keys] over the K tile
        if (tid < 32){
            float s = 0.f;
            #pragma unroll
            for (int c = 0; c < 8; c++) s += psum[tid * 8 + c];
            lst[tid] += s;
        }
        {
            const short* src = Vt + (size_t)b * 256 * 4096 + kb * 64;
            #pragma unroll
            for (int i = 0; i < 8; i++){
                int idx = tid + i * 256, r = idx >> 3, c = (idx & 7) * 8;
                *(short8_t*)&KVs[r * 72 + c] = *(const short8_t*)(src + (size_t)r * 4096 + c);
            }
        }
        __syncthreads();
        // PV: wave wv owns channels [wv*64, wv*64+64)
        #pragma unroll
        for (int kk = 0; kk < 2; kk++){
            int off = kk * 32 + lq * 8;
            short8_t a0 = *(short8_t*)&Pls[lrow * 72 + off];
            short8_t a1 = *(short8_t*)&Pls[(16 + lrow) * 72 + off];
            #pragma unroll
            for (int nt = 0; nt < 4; nt++){
                short8_t bf = *(short8_t*)&KVs[(wv * 64 + nt * 16 + lrow) * 72 + off];
                oacc[0][nt] = mfma16(a0, bf, oacc[0][nt]);
                oacc[1][nt] = mfma16(a1, bf, oacc[1][nt]);
            }
        }
    }
    // epilogue: O /= l, write back in ORIGINAL n = h*64 + w order
    #pragma unroll
    for (int rg = 0; rg < 2; rg++)
        #pragma unroll
        for (int r = 0; r < 4; r++){
            int row = rg * 16 + lq * 4 + r;
            float inv = 1.f / lst[row];
            int h = hh * 32 + row;
            size_t base = ((size_t)b * 4096 + h * 64 + w) * 256;
            #pragma unroll
            for (int nt = 0; nt < 4; nt++)
                hb[base + wv * 64 + nt * 16 + lrow] = f2bf(oacc[rg][nt][r] * inv);
        }
}

// ---------- K5: final proj + bias + residual, coalesced f32 store to (B,C,H,W) ----------
__global__ __launch_bounds__(256) void final_gemm(const short* __restrict__ hbuf,
    const short* __restrict__ wT3, const float* __restrict__ b3,
    const float* __restrict__ x, float* __restrict__ out)
{
    __shared__ short As[64 * 72];
    __shared__ short Bs[64 * 72];
    __shared__ float CT[64 * 65];

    const int tid = threadIdx.x;
    const int m0 = blockIdx.x * 64;        // 64 consecutive n -> fixed h, w = 0..63
    const int d0 = blockIdx.y * 64;
    const int wv = tid >> 6, lane = tid & 63;
    const int wrow = (wv >> 1) * 32, wcol = (wv & 1) * 32;
    const int lrow = lane & 15, lq = lane >> 4;

    f32x4 acc[2][2] = {};
    for (int k0 = 0; k0 < 256; k0 += 64){
        __syncthreads();
        #pragma unroll
        for (int i = 0; i < 2; i++){
            int idx = tid + i * 256, r = idx >> 3, c = (idx & 7) * 8;
            *(short8_t*)&As[r * 72 + c] = *(const short8_t*)(hbuf + (size_t)(m0 + r) * 256 + k0 + c);
            *(short8_t*)&Bs[r * 72 + c] = *(const short8_t*)(wT3 + (size_t)(d0 + r) * 256 + k0 + c);
        }
        __syncthreads();
        #pragma unroll
        for (int kk = 0; kk < 2; kk++){
            int off = kk * 32 + lq * 8;
            short8_t a0  = *(short8_t*)&As[(wrow + lrow) * 72 + off];
            short8_t a1  = *(short8_t*)&As[(wrow + 16 + lrow) * 72 + off];
            short8_t b0v = *(short8_t*)&Bs[(wcol + lrow) * 72 + off];
            short8_t b1v = *(short8_t*)&Bs[(wcol + 16 + lrow) * 72 + off];
            acc[0][0] = mfma16(a0, b0v, acc[0][0]);
            acc[0][1] = mfma16(a0, b1v, acc[0][1]);
            acc[1][0] = mfma16(a1, b0v, acc[1][0]);
            acc[1][1] = mfma16(a1, b1v, acc[1][1]);
        }
    }
    #pragma unroll
    for (int i = 0; i < 2; i++)
      #pragma unroll
      for (int j = 0; j < 2; j++)
        #pragma unroll
        for (int r = 0; r < 4; r++){
            int row = wrow + i * 16 + lq * 4 + r;
            int col = wcol + j * 16 + lrow;
            CT[col * 65 + row] = acc[i][j][r] + b3[d0 + col];
        }
    __syncthreads();
    int b = m0 >> 12, n0 = m0 & 4095, hrow = n0 >> 6;
    int dr = tid >> 2, wc = (tid & 3) * 16;
    size_t base = ((size_t)(b * 256 + d0 + dr) * 64 + hrow) * 64 + wc;
    const f32x4* xp = (const f32x4*)(x + base);
    f32x4* op = (f32x4*)(out + base);
    #pragma unroll
    for (int q = 0; q < 4; q++){
        f32x4 xv = xp[q], o;
        #pragma unroll
        for (int j = 0; j < 4; j++) o[j] = xv[j] + CT[dr * 65 + wc + q * 4 + j];
        op[q] = o;
    }
}

extern "C" void kernel_launch(void* const* d_in, const int* in_sizes, int n_in,
                              void* d_out, int out_size, void* d_ws, size_t ws_size,
                              hipStream_t stream)
{
    const float* x   = (const float*)d_in[0];
    const float* gnw = (const float*)d_in[1];
    const float* gnb = (const float*)d_in[2];
    const float* w0  = (const float*)d_in[3];
    const float* b0  = (const float*)d_in[4];
    const float* w1  = (const float*)d_in[5];
    const float* b1  = (const float*)d_in[6];
    const float* w2  = (const float*)d_in[7];
    const float* b2  = (const float*)d_in[8];
    const float* w3  = (const float*)d_in[9];
    const float* b3  = (const float*)d_in[10];
    float* out = (float*)d_out;

    char* ws = (char*)d_ws;
    short* wT  = (short*)(ws);                  // 4 * 256*256 bf16  = 512 KB
    short* hn  = (short*)(ws + 524288);         // (B, m~, C) bf16   = 8 MB
    short* Qb  = (short*)(ws + 8912896);        // 8 MB
    short* Kb  = (short*)(ws + 17301504);       // 8 MB
    short* Vt  = (short*)(ws + 25690112);       // (B, C, m~) 8 MB
    short* hb  = (short*)(ws + 34078720);       // (B, n, C)  8 MB   (end 40.5 MB)

    prep_w   <<<1024, 256, 0, stream>>>(w0, w1, w2, w3, wT);
    gn_kernel<<<2048, 256, 0, stream>>>(x, gnw, gnb, hn);
    qkv_gemm <<<dim3(256, 12), 256, 0, stream>>>(hn, wT, b0, b1, b2, Qb, Kb, Vt);
    attn_kernel<<<dim3(128, 4), 256, 0, stream>>>(Qb, Kb, Vt, hb);
    final_gemm<<<dim3(256, 4), 256, 0, stream>>>(hb, wT + 3 * 65536, b3, x, out);
}

// Round 3
// 271.173 us; speedup vs baseline: 1.3993x; 1.3993x over previous
//
#include <hip/hip_runtime.h>
#include <math.h>

#define LOG2E 1.4426950408889634f

typedef __attribute__((ext_vector_type(8))) __bf16 bf16x8_t;
typedef __attribute__((ext_vector_type(8))) short short8_t;
typedef __attribute__((ext_vector_type(4))) float f32x4;

static __device__ __forceinline__ short f2bf(float f){
    unsigned u = __builtin_bit_cast(unsigned, f);
    unsigned r = (u + 0x7fffu + ((u >> 16) & 1u)) >> 16;
    return (short)r;
}

static __device__ __forceinline__ f32x4 mfma16(short8_t a, short8_t b, f32x4 c){
    return __builtin_amdgcn_mfma_f32_16x16x32_bf16(
        __builtin_bit_cast(bf16x8_t, a), __builtin_bit_cast(bf16x8_t, b), c, 0, 0, 0);
}

template<int PAT>
static __device__ __forceinline__ float swz_f32(float v){
    return __builtin_bit_cast(float,
        __builtin_amdgcn_ds_swizzle(__builtin_bit_cast(int, v), PAT));
}

// butterfly max/sum over 16 lanes (xor 1,2,4,8) for each element of an f32x4
static __device__ __forceinline__ void bfly_max16(f32x4& v){
    #pragma unroll
    for (int r = 0; r < 4; r++) v[r] = fmaxf(v[r], swz_f32<0x041F>(v[r]));
    #pragma unroll
    for (int r = 0; r < 4; r++) v[r] = fmaxf(v[r], swz_f32<0x081F>(v[r]));
    #pragma unroll
    for (int r = 0; r < 4; r++) v[r] = fmaxf(v[r], swz_f32<0x101F>(v[r]));
    #pragma unroll
    for (int r = 0; r < 4; r++) v[r] = fmaxf(v[r], swz_f32<0x201F>(v[r]));
}
static __device__ __forceinline__ void bfly_sum16(f32x4& v){
    #pragma unroll
    for (int r = 0; r < 4; r++) v[r] += swz_f32<0x041F>(v[r]);
    #pragma unroll
    for (int r = 0; r < 4; r++) v[r] += swz_f32<0x081F>(v[r]);
    #pragma unroll
    for (int r = 0; r < 4; r++) v[r] += swz_f32<0x101F>(v[r]);
    #pragma unroll
    for (int r = 0; r < 4; r++) v[r] += swz_f32<0x201F>(v[r]);
}

// ---------- K1: weights -> bf16, transposed to [mat][d][c] ----------
__global__ __launch_bounds__(256) void prep_w(const float* __restrict__ w0,
    const float* __restrict__ w1, const float* __restrict__ w2,
    const float* __restrict__ w3, short* __restrict__ wT)
{
    int t = blockIdx.x * 256 + threadIdx.x;        // 4 * 65536 total
    int mat = t >> 16, r = t & 65535, d = r >> 8, c = r & 255;
    const float* src = mat == 0 ? w0 : mat == 1 ? w1 : mat == 2 ? w2 : w3;
    wT[t] = f2bf(src[c * 256 + d]);
}

// ---------- K2: per-pixel GroupNorm (G=32, 8 ch/group), write hn (B, m~=w*64+h, C) bf16 ----------
__global__ __launch_bounds__(256) void gn_kernel(const float* __restrict__ x,
    const float* __restrict__ gnw, const float* __restrict__ gnb,
    short* __restrict__ hn)
{
    int flat = blockIdx.x * 256 + threadIdx.x;     // b*(32*4096) + g*4096 + n
    int n = flat & 4095, g = (flat >> 12) & 31, b = flat >> 17;
    const float* xp = x + (size_t)(b * 256 + g * 8) * 4096 + n;
    float v[8], s = 0.f, s2 = 0.f;
    #pragma unroll
    for (int k = 0; k < 8; k++){ float t = xp[(size_t)k * 4096]; v[k] = t; s += t; s2 += t * t; }
    float mean = s * 0.125f;
    float var  = s2 * 0.125f - mean * mean;
    float inv  = rsqrtf(var + 1e-6f);
    int h = n >> 6, w = n & 63, m = w * 64 + h;    // spatial transpose: column-major index
    short o[8];
    #pragma unroll
    for (int k = 0; k < 8; k++)
        o[k] = f2bf((v[k] - mean) * inv * gnw[g * 8 + k] + gnb[g * 8 + k]);
    *(short8_t*)(hn + (size_t)(b * 4096 + m) * 256 + g * 8) = *(short8_t*)o;
}

// ---------- K3: QKV GEMM. A = hn [16384 x 256], B = wT[mat] (d-major). ----------
__global__ __launch_bounds__(256) void qkv_gemm(const short* __restrict__ hn,
    const short* __restrict__ wT, const float* __restrict__ bq,
    const float* __restrict__ bk, const float* __restrict__ bv,
    short* __restrict__ Q, short* __restrict__ K, short* __restrict__ Vt)
{
    __shared__ short As[64 * 72];
    __shared__ short Bs[64 * 72];
    __shared__ float CT[64 * 65];

    const int tid = threadIdx.x;
    const int m0 = blockIdx.x * 64;
    const int by = blockIdx.y;
    const int mat = by >> 2;                 // 0=Q 1=K 2=V
    const int d0 = (by & 3) * 64;
    const short* w = wT + mat * 65536;
    const float* bias = mat == 0 ? bq : mat == 1 ? bk : bv;

    const int wv = tid >> 6, lane = tid & 63;
    const int wrow = (wv >> 1) * 32, wcol = (wv & 1) * 32;
    const int lrow = lane & 15, lq = lane >> 4;

    f32x4 acc[2][2] = {};

    for (int k0 = 0; k0 < 256; k0 += 64){
        __syncthreads();
        #pragma unroll
        for (int i = 0; i < 2; i++){
            int idx = tid + i * 256, r = idx >> 3, c = (idx & 7) * 8;
            *(short8_t*)&As[r * 72 + c] = *(const short8_t*)(hn + (size_t)(m0 + r) * 256 + k0 + c);
            *(short8_t*)&Bs[r * 72 + c] = *(const short8_t*)(w  + (size_t)(d0 + r) * 256 + k0 + c);
        }
        __syncthreads();
        #pragma unroll
        for (int kk = 0; kk < 2; kk++){
            int off = kk * 32 + lq * 8;
            short8_t a0  = *(short8_t*)&As[(wrow + lrow) * 72 + off];
            short8_t a1  = *(short8_t*)&As[(wrow + 16 + lrow) * 72 + off];
            short8_t b0v = *(short8_t*)&Bs[(wcol + lrow) * 72 + off];
            short8_t b1v = *(short8_t*)&Bs[(wcol + 16 + lrow) * 72 + off];
            acc[0][0] = mfma16(a0, b0v, acc[0][0]);
            acc[0][1] = mfma16(a0, b1v, acc[0][1]);
            acc[1][0] = mfma16(a1, b0v, acc[1][0]);
            acc[1][1] = mfma16(a1, b1v, acc[1][1]);
        }
    }

    if (mat < 2){
        short* out = (mat == 0) ? Q : K;
        #pragma unroll
        for (int i = 0; i < 2; i++)
          #pragma unroll
          for (int j = 0; j < 2; j++)
            #pragma unroll
            for (int r = 0; r < 4; r++){
                int row = wrow + i * 16 + lq * 4 + r;
                int col = wcol + j * 16 + lrow;
                out[(size_t)(m0 + row) * 256 + d0 + col] = f2bf(acc[i][j][r] + bias[d0 + col]);
            }
    } else {
        #pragma unroll
        for (int i = 0; i < 2; i++)
          #pragma unroll
          for (int j = 0; j < 2; j++)
            #pragma unroll
            for (int r = 0; r < 4; r++){
                int row = wrow + i * 16 + lq * 4 + r;
                int col = wcol + j * 16 + lrow;
                CT[col * 65 + row] = acc[i][j][r] + bias[d0 + col];
            }
        __syncthreads();
        int b = m0 >> 12, mloc = m0 & 4095;
        int dr = tid >> 2, wc = (tid & 3) * 16;
        short tmp[16];
        #pragma unroll
        for (int j = 0; j < 16; j++) tmp[j] = f2bf(CT[dr * 65 + wc + j]);
        short* dst = Vt + (size_t)(b * 256 + d0 + dr) * 4096 + mloc + wc;
        *(short8_t*)dst = *(short8_t*)tmp;
        *(short8_t*)(dst + 8) = *(short8_t*)(tmp + 8);
    }
}

// ---------- K4: flash attention, balanced 65-iteration blocks ----------
// block = (pair pr, hh, b): segment 0 = column w=63-pr, segment 1 = column w=pr.
// 512 threads / 8 waves: wave = (rowgroup rg2 = wv>>2) x (key colgroup kc = wv&3).
// Softmax row-reductions in-register via ds_swizzle; K/V staged with reg prefetch.
__global__ __launch_bounds__(512, 2) void attn_kernel(const short* __restrict__ Q,
    const short* __restrict__ K, const short* __restrict__ Vt,
    short* __restrict__ hb)
{
    __shared__ short Ks[64 * 264];     // K tile [64 keys][256 ch], padded
    __shared__ short Vs[256 * 72];     // V^T tile [256 ch][64 keys], padded
    __shared__ short Pls[32 * 72];     // P bf16 [32 q][64 keys], padded
    __shared__ float mst[32], lst[32], alph[32];
    __shared__ float pmax2[32 * 4], psum2[32 * 4];

    const int tid = threadIdx.x, lane = tid & 63, wv = tid >> 6;
    const int l15 = lane & 15, lq = lane >> 4;
    const int rg2 = wv >> 2, kc = wv & 3;
    const int b = blockIdx.y;
    const int pr = blockIdx.x >> 1, hh = blockIdx.x & 1;

    for (int seg = 0; seg < 2; seg++){
        const int w = (seg == 0) ? (63 - pr) : pr;
        const int q0 = w * 64 + hh * 32;

        __syncthreads();   // protect stats/LDS from previous segment
        if (tid < 32){ mst[tid] = -1e30f; lst[tid] = 0.f; }
        if (tid < 128) psum2[tid] = 0.f;

        // Q fragments in registers: rows rg2*16 + l15, all 256 k
        short8_t qf[8];
        {
            const short* qp = Q + ((size_t)b * 4096 + q0 + rg2 * 16 + l15) * 256;
            #pragma unroll
            for (int ks = 0; ks < 8; ks++)
                qf[ks] = *(const short8_t*)(qp + ks * 32 + lq * 8);
        }
        f32x4 oacc[4] = {};

        // prefetch kb = 0
        short8_t kreg[4], vreg[4];
        {
            const short* ksrc = K  + (size_t)b * 4096 * 256;
            const short* vsrc = Vt + (size_t)b * 256 * 4096;
            #pragma unroll
            for (int i = 0; i < 4; i++){
                int idx = tid + i * 512;
                kreg[i] = *(const short8_t*)(ksrc + (size_t)(idx >> 5) * 256 + (idx & 31) * 8);
                vreg[i] = *(const short8_t*)(vsrc + (size_t)(idx >> 3) * 4096 + (idx & 7) * 8);
            }
        }

        for (int kb = 0; kb <= w; kb++){
            __syncthreads();                       // Ks/Vs free (prev PV done); stats init visible
            #pragma unroll
            for (int i = 0; i < 4; i++){
                int idx = tid + i * 512;
                { int r = idx >> 5, c = (idx & 31) * 8; *(short8_t*)&Ks[r * 264 + c] = kreg[i]; }
                { int r = idx >> 3, c = (idx & 7)  * 8; *(short8_t*)&Vs[r * 72  + c] = vreg[i]; }
            }
            if (kb < w){
                const short* ksrc = K  + ((size_t)b * 4096 + (kb + 1) * 64) * 256;
                const short* vsrc = Vt + (size_t)b * 256 * 4096 + (kb + 1) * 64;
                #pragma unroll
                for (int i = 0; i < 4; i++){
                    int idx = tid + i * 512;
                    kreg[i] = *(const short8_t*)(ksrc + (size_t)(idx >> 5) * 256 + (idx & 31) * 8);
                    vreg[i] = *(const short8_t*)(vsrc + (size_t)(idx >> 3) * 4096 + (idx & 7) * 8);
                }
            }
            __syncthreads();

            // QK: one 16x16 S tile per wave
            f32x4 s0 = {};
            #pragma unroll
            for (int ks = 0; ks < 8; ks++){
                short8_t bf = *(short8_t*)&Ks[(kc * 16 + l15) * 264 + ks * 32 + lq * 8];
                s0 = mfma16(qf[ks], bf, s0);
            }
            #pragma unroll
            for (int r = 0; r < 4; r++) s0[r] *= 0.0625f;

            // in-register row max across the 16 lanes of each C-fragment row
            f32x4 mx = s0;
            bfly_max16(mx);
            if (l15 == 0){
                #pragma unroll
                for (int r = 0; r < 4; r++) pmax2[(rg2 * 16 + lq * 4 + r) * 4 + kc] = mx[r];
            }
            __syncthreads();

            // running max / alpha / deferred-l (32 threads)
            if (tid < 32){
                float mo = mst[tid];
                float pm = fmaxf(fmaxf(pmax2[tid * 4], pmax2[tid * 4 + 1]),
                                 fmaxf(pmax2[tid * 4 + 2], pmax2[tid * 4 + 3]));
                float l  = lst[tid] + psum2[tid * 4] + psum2[tid * 4 + 1]
                                    + psum2[tid * 4 + 2] + psum2[tid * 4 + 3];
                float mn = fmaxf(mo, pm);
                float al = exp2f((mo - mn) * LOG2E);
                alph[tid] = al; mst[tid] = mn; lst[tid] = l * al;
            }
            __syncthreads();

            // exp in regs, write P (C-layout scatter), row-sum via swizzle, rescale O
            f32x4 p;
            #pragma unroll
            for (int r = 0; r < 4; r++){
                float m = mst[rg2 * 16 + lq * 4 + r];
                p[r] = exp2f((s0[r] - m) * LOG2E);
            }
            #pragma unroll
            for (int r = 0; r < 4; r++)
                Pls[(rg2 * 16 + lq * 4 + r) * 72 + kc * 16 + l15] = f2bf(p[r]);
            f32x4 sm = p;
            bfly_sum16(sm);
            if (l15 == 0){
                #pragma unroll
                for (int r = 0; r < 4; r++) psum2[(rg2 * 16 + lq * 4 + r) * 4 + kc] = sm[r];
            }
            #pragma unroll
            for (int r = 0; r < 4; r++){
                float al = alph[rg2 * 16 + lq * 4 + r];
                #pragma unroll
                for (int nt = 0; nt < 4; nt++) oacc[nt][r] *= al;
            }
            __syncthreads();

            // PV: wave owns channels kc*64 .. kc*64+64
            #pragma unroll
            for (int kk = 0; kk < 2; kk++){
                short8_t a = *(short8_t*)&Pls[(rg2 * 16 + l15) * 72 + kk * 32 + lq * 8];
                #pragma unroll
                for (int nt = 0; nt < 4; nt++){
                    short8_t bfr = *(short8_t*)&Vs[(kc * 64 + nt * 16 + l15) * 72 + kk * 32 + lq * 8];
                    oacc[nt] = mfma16(a, bfr, oacc[nt]);
                }
            }
        }

        __syncthreads();
        if (tid < 32)
            lst[tid] += psum2[tid * 4] + psum2[tid * 4 + 1]
                      + psum2[tid * 4 + 2] + psum2[tid * 4 + 3];
        __syncthreads();

        // epilogue: O /= l, write back in ORIGINAL n = h*64 + w order
        #pragma unroll
        for (int r = 0; r < 4; r++){
            int row = rg2 * 16 + lq * 4 + r;
            float inv = 1.f / lst[row];
            int h = hh * 32 + row;
            size_t base = ((size_t)b * 4096 + h * 64 + w) * 256;
            #pragma unroll
            for (int nt = 0; nt < 4; nt++)
                hb[base + kc * 64 + nt * 16 + l15] = f2bf(oacc[nt][r] * inv);
        }
    }
}

// ---------- K5: final proj + bias + residual, coalesced f32 store to (B,C,H,W) ----------
__global__ __launch_bounds__(256) void final_gemm(const short* __restrict__ hbuf,
    const short* __restrict__ wT3, const float* __restrict__ b3,
    const float* __restrict__ x, float* __restrict__ out)
{
    __shared__ short As[64 * 72];
    __shared__ short Bs[64 * 72];
    __shared__ float CT[64 * 65];

    const int tid = threadIdx.x;
    const int m0 = blockIdx.x * 64;        // 64 consecutive n -> fixed h, w = 0..63
    const int d0 = blockIdx.y * 64;
    const int wv = tid >> 6, lane = tid & 63;
    const int wrow = (wv >> 1) * 32, wcol = (wv & 1) * 32;
    const int lrow = lane & 15, lq = lane >> 4;

    f32x4 acc[2][2] = {};
    for (int k0 = 0; k0 < 256; k0 += 64){
        __syncthreads();
        #pragma unroll
        for (int i = 0; i < 2; i++){
            int idx = tid + i * 256, r = idx >> 3, c = (idx & 7) * 8;
            *(short8_t*)&As[r * 72 + c] = *(const short8_t*)(hbuf + (size_t)(m0 + r) * 256 + k0 + c);
            *(short8_t*)&Bs[r * 72 + c] = *(const short8_t*)(wT3 + (size_t)(d0 + r) * 256 + k0 + c);
        }
        __syncthreads();
        #pragma unroll
        for (int kk = 0; kk < 2; kk++){
            int off = kk * 32 + lq * 8;
            short8_t a0  = *(short8_t*)&As[(wrow + lrow) * 72 + off];
            short8_t a1  = *(short8_t*)&As[(wrow + 16 + lrow) * 72 + off];
            short8_t b0v = *(short8_t*)&Bs[(wcol + lrow) * 72 + off];
            short8_t b1v = *(short8_t*)&Bs[(wcol + 16 + lrow) * 72 + off];
            acc[0][0] = mfma16(a0, b0v, acc[0][0]);
            acc[0][1] = mfma16(a0, b1v, acc[0][1]);
            acc[1][0] = mfma16(a1, b0v, acc[1][0]);
            acc[1][1] = mfma16(a1, b1v, acc[1][1]);
        }
    }
    #pragma unroll
    for (int i = 0; i < 2; i++)
      #pragma unroll
      for (int j = 0; j < 2; j++)
        #pragma unroll
        for (int r = 0; r < 4; r++){
            int row = wrow + i * 16 + lq * 4 + r;
            int col = wcol + j * 16 + lrow;
            CT[col * 65 + row] = acc[i][j][r] + b3[d0 + col];
        }
    __syncthreads();
    int b = m0 >> 12, n0 = m0 & 4095, hrow = n0 >> 6;
    int dr = tid >> 2, wc = (tid & 3) * 16;
    size_t base = ((size_t)(b * 256 + d0 + dr) * 64 + hrow) * 64 + wc;
    const f32x4* xp = (const f32x4*)(x + base);
    f32x4* op = (f32x4*)(out + base);
    #pragma unroll
    for (int q = 0; q < 4; q++){
        f32x4 xv = xp[q], o;
        #pragma unroll
        for (int j = 0; j < 4; j++) o[j] = xv[j] + CT[dr * 65 + wc + q * 4 + j];
        op[q] = o;
    }
}

extern "C" void kernel_launch(void* const* d_in, const int* in_sizes, int n_in,
                              void* d_out, int out_size, void* d_ws, size_t ws_size,
                              hipStream_t stream)
{
    const float* x   = (const float*)d_in[0];
    const float* gnw = (const float*)d_in[1];
    const float* gnb = (const float*)d_in[2];
    const float* w0  = (const float*)d_in[3];
    const float* b0  = (const float*)d_in[4];
    const float* w1  = (const float*)d_in[5];
    const float* b1  = (const float*)d_in[6];
    const float* w2  = (const float*)d_in[7];
    const float* b2  = (const float*)d_in[8];
    const float* w3  = (const float*)d_in[9];
    const float* b3  = (const float*)d_in[10];
    float* out = (float*)d_out;

    char* ws = (char*)d_ws;
    short* wT  = (short*)(ws);                  // 4 * 256*256 bf16  = 512 KB
    short* hn  = (short*)(ws + 524288);         // (B, m~, C) bf16   = 8 MB
    short* Qb  = (short*)(ws + 8912896);        // 8 MB
    short* Kb  = (short*)(ws + 17301504);       // 8 MB
    short* Vt  = (short*)(ws + 25690112);       // (B, C, m~) 8 MB
    short* hb  = (short*)(ws + 34078720);       // (B, n, C)  8 MB   (end 40.5 MB)

    prep_w   <<<1024, 256, 0, stream>>>(w0, w1, w2, w3, wT);
    gn_kernel<<<2048, 256, 0, stream>>>(x, gnw, gnb, hn);
    qkv_gemm <<<dim3(256, 12), 256, 0, stream>>>(hn, wT, b0, b1, b2, Qb, Kb, Vt);
    attn_kernel<<<dim3(64, 4), 512, 0, stream>>>(Qb, Kb, Vt, hb);
    final_gemm<<<dim3(256, 4), 256, 0, stream>>>(hb, wT + 3 * 65536, b3, x, out);
}

// Round 4
// 267.460 us; speedup vs baseline: 1.4187x; 1.0139x over previous
//
#include <hip/hip_runtime.h>
#include <math.h>

#define LOG2E 1.4426950408889634f

typedef __attribute__((ext_vector_type(8))) __bf16 bf16x8_t;
typedef __attribute__((ext_vector_type(8))) short short8_t;
typedef __attribute__((ext_vector_type(4))) float f32x4;

static __device__ __forceinline__ short f2bf(float f){
    unsigned u = __builtin_bit_cast(unsigned, f);
    unsigned r = (u + 0x7fffu + ((u >> 16) & 1u)) >> 16;
    return (short)r;
}

static __device__ __forceinline__ f32x4 mfma16(short8_t a, short8_t b, f32x4 c){
    return __builtin_amdgcn_mfma_f32_16x16x32_bf16(
        __builtin_bit_cast(bf16x8_t, a), __builtin_bit_cast(bf16x8_t, b), c, 0, 0, 0);
}

// DPP row-rotate (within 16-lane row) — runs on VALU pipe, not LDS.
template<int CTRL>
static __device__ __forceinline__ float dppmov(float v){
    return __builtin_bit_cast(float, __builtin_amdgcn_update_dpp(
        0, __builtin_bit_cast(int, v), CTRL, 0xF, 0xF, true));
}
// full 16-lane reduction via rotate 1,2,4,8 (ror ctrl = 0x120+n)
static __device__ __forceinline__ void rowred_max(f32x4& v){
    #pragma unroll
    for (int r = 0; r < 4; r++){
        float t = v[r];
        t = fmaxf(t, dppmov<0x121>(t));
        t = fmaxf(t, dppmov<0x122>(t));
        t = fmaxf(t, dppmov<0x124>(t));
        t = fmaxf(t, dppmov<0x128>(t));
        v[r] = t;
    }
}
static __device__ __forceinline__ void rowred_sum(f32x4& v){
    #pragma unroll
    for (int r = 0; r < 4; r++){
        float t = v[r];
        t += dppmov<0x121>(t);
        t += dppmov<0x122>(t);
        t += dppmov<0x124>(t);
        t += dppmov<0x128>(t);
        v[r] = t;
    }
}

// ---------- K1: weights -> bf16, transposed to [mat][d][c] ----------
__global__ __launch_bounds__(256) void prep_w(const float* __restrict__ w0,
    const float* __restrict__ w1, const float* __restrict__ w2,
    const float* __restrict__ w3, short* __restrict__ wT)
{
    int t = blockIdx.x * 256 + threadIdx.x;        // 4 * 65536 total
    int mat = t >> 16, r = t & 65535, d = r >> 8, c = r & 255;
    const float* src = mat == 0 ? w0 : mat == 1 ? w1 : mat == 2 ? w2 : w3;
    wT[t] = f2bf(src[c * 256 + d]);
}

// ---------- K2: per-pixel GroupNorm (G=32, 8 ch/group), write hn (B, m~=w*64+h, C) bf16 ----------
__global__ __launch_bounds__(256) void gn_kernel(const float* __restrict__ x,
    const float* __restrict__ gnw, const float* __restrict__ gnb,
    short* __restrict__ hn)
{
    int flat = blockIdx.x * 256 + threadIdx.x;     // b*(32*4096) + g*4096 + n
    int n = flat & 4095, g = (flat >> 12) & 31, b = flat >> 17;
    const float* xp = x + (size_t)(b * 256 + g * 8) * 4096 + n;
    float v[8], s = 0.f, s2 = 0.f;
    #pragma unroll
    for (int k = 0; k < 8; k++){ float t = xp[(size_t)k * 4096]; v[k] = t; s += t; s2 += t * t; }
    float mean = s * 0.125f;
    float var  = s2 * 0.125f - mean * mean;
    float inv  = rsqrtf(var + 1e-6f);
    int h = n >> 6, w = n & 63, m = w * 64 + h;    // spatial transpose: column-major index
    short o[8];
    #pragma unroll
    for (int k = 0; k < 8; k++)
        o[k] = f2bf((v[k] - mean) * inv * gnw[g * 8 + k] + gnb[g * 8 + k]);
    *(short8_t*)(hn + (size_t)(b * 4096 + m) * 256 + g * 8) = *(short8_t*)o;
}

// ---------- K3: QKV GEMM. A = hn [16384 x 256], B = wT[mat] (d-major). ----------
__global__ __launch_bounds__(256) void qkv_gemm(const short* __restrict__ hn,
    const short* __restrict__ wT, const float* __restrict__ bq,
    const float* __restrict__ bk, const float* __restrict__ bv,
    short* __restrict__ Q, short* __restrict__ K, short* __restrict__ Vt)
{
    __shared__ short As[64 * 72];
    __shared__ short Bs[64 * 72];
    __shared__ float CT[64 * 65];

    const int tid = threadIdx.x;
    const int m0 = blockIdx.x * 64;
    const int by = blockIdx.y;
    const int mat = by >> 2;                 // 0=Q 1=K 2=V
    const int d0 = (by & 3) * 64;
    const short* w = wT + mat * 65536;
    const float* bias = mat == 0 ? bq : mat == 1 ? bk : bv;

    const int wv = tid >> 6, lane = tid & 63;
    const int wrow = (wv >> 1) * 32, wcol = (wv & 1) * 32;
    const int lrow = lane & 15, lq = lane >> 4;

    f32x4 acc[2][2] = {};

    for (int k0 = 0; k0 < 256; k0 += 64){
        __syncthreads();
        #pragma unroll
        for (int i = 0; i < 2; i++){
            int idx = tid + i * 256, r = idx >> 3, c = (idx & 7) * 8;
            *(short8_t*)&As[r * 72 + c] = *(const short8_t*)(hn + (size_t)(m0 + r) * 256 + k0 + c);
            *(short8_t*)&Bs[r * 72 + c] = *(const short8_t*)(w  + (size_t)(d0 + r) * 256 + k0 + c);
        }
        __syncthreads();
        #pragma unroll
        for (int kk = 0; kk < 2; kk++){
            int off = kk * 32 + lq * 8;
            short8_t a0  = *(short8_t*)&As[(wrow + lrow) * 72 + off];
            short8_t a1  = *(short8_t*)&As[(wrow + 16 + lrow) * 72 + off];
            short8_t b0v = *(short8_t*)&Bs[(wcol + lrow) * 72 + off];
            short8_t b1v = *(short8_t*)&Bs[(wcol + 16 + lrow) * 72 + off];
            acc[0][0] = mfma16(a0, b0v, acc[0][0]);
            acc[0][1] = mfma16(a0, b1v, acc[0][1]);
            acc[1][0] = mfma16(a1, b0v, acc[1][0]);
            acc[1][1] = mfma16(a1, b1v, acc[1][1]);
        }
    }

    if (mat < 2){
        short* out = (mat == 0) ? Q : K;
        #pragma unroll
        for (int i = 0; i < 2; i++)
          #pragma unroll
          for (int j = 0; j < 2; j++)
            #pragma unroll
            for (int r = 0; r < 4; r++){
                int row = wrow + i * 16 + lq * 4 + r;
                int col = wcol + j * 16 + lrow;
                out[(size_t)(m0 + row) * 256 + d0 + col] = f2bf(acc[i][j][r] + bias[d0 + col]);
            }
    } else {
        #pragma unroll
        for (int i = 0; i < 2; i++)
          #pragma unroll
          for (int j = 0; j < 2; j++)
            #pragma unroll
            for (int r = 0; r < 4; r++){
                int row = wrow + i * 16 + lq * 4 + r;
                int col = wcol + j * 16 + lrow;
                CT[col * 65 + row] = acc[i][j][r] + bias[d0 + col];
            }
        __syncthreads();
        int b = m0 >> 12, mloc = m0 & 4095;
        int dr = tid >> 2, wc = (tid & 3) * 16;
        short tmp[16];
        #pragma unroll
        for (int j = 0; j < 16; j++) tmp[j] = f2bf(CT[dr * 65 + wc + j]);
        short* dst = Vt + (size_t)(b * 256 + d0 + dr) * 4096 + mloc + wc;
        *(short8_t*)dst = *(short8_t*)tmp;
        *(short8_t*)(dst + 8) = *(short8_t*)(tmp + 8);
    }
}

// ---------- K4: flash attention, 3 barriers/iter, dbuf LDS staging, DPP softmax ----------
// block = (pair pr, hh, b): segment 0 = column w=63-pr, segment 1 = column w=pr (65 iters total).
// 512 threads / 8 waves: wave = (rowgroup rg2 = wv>>2) x (key colgroup kc = wv&3).
__global__ __launch_bounds__(512, 2) void attn_kernel(const short* __restrict__ Q,
    const short* __restrict__ K, const short* __restrict__ Vt,
    short* __restrict__ hb)
{
    __shared__ short Ks[2][64 * 264];   // K tile dbuf [64 keys][256 ch], padded   (66 KB)
    __shared__ short Vs[2][256 * 72];   // V^T tile dbuf [256 ch][64 keys], padded (72 KB)
    __shared__ short Pls[32 * 72];      // P bf16 [32 q][64 keys], padded          (4.5 KB)
    __shared__ float pmaxs[32 * 4];     // per-row per-kc partial max              (0.5 KB)

    const int tid = threadIdx.x, lane = tid & 63, wv = tid >> 6;
    const int l15 = lane & 15, lq = lane >> 4;
    const int rg2 = wv >> 2, kc = wv & 3;
    const int b = blockIdx.y;
    const int pr = blockIdx.x >> 1, hh = blockIdx.x & 1;

    const short* Kbase = K  + (size_t)b * 4096 * 256;
    const short* Vbase = Vt + (size_t)b * 256 * 4096;

    for (int seg = 0; seg < 2; seg++){
        const int w = (seg == 0) ? (63 - pr) : pr;
        const int q0 = w * 64 + hh * 32;

        // Q fragments in registers: rows rg2*16 + l15, all 256 k
        short8_t qf[8];
        {
            const short* qp = Q + ((size_t)b * 4096 + q0 + rg2 * 16 + l15) * 256;
            #pragma unroll
            for (int ks = 0; ks < 8; ks++)
                qf[ks] = *(const short8_t*)(qp + ks * 32 + lq * 8);
        }
        f32x4 oacc[4] = {};
        float m_reg[4], l_reg[4], al_reg[4];
        #pragma unroll
        for (int r = 0; r < 4; r++){ m_reg[r] = -1e30f; l_reg[r] = 0.f; }

        // pre-stage tile 0 into buffer 0; prefetch tile 1 into regs
        short8_t kreg[4], vreg[4];
        #pragma unroll
        for (int i = 0; i < 4; i++){
            int idx = tid + i * 512;
            kreg[i] = *(const short8_t*)(Kbase + (size_t)(idx >> 5) * 256 + (idx & 31) * 8);
            vreg[i] = *(const short8_t*)(Vbase + (size_t)(idx >> 3) * 4096 + (idx & 7) * 8);
        }
        #pragma unroll
        for (int i = 0; i < 4; i++){
            int idx = tid + i * 512;
            *(short8_t*)&Ks[0][(idx >> 5) * 264 + (idx & 31) * 8] = kreg[i];
            *(short8_t*)&Vs[0][(idx >> 3) * 72  + (idx & 7)  * 8] = vreg[i];
        }
        if (w >= 1){
            #pragma unroll
            for (int i = 0; i < 4; i++){
                int idx = tid + i * 512;
                kreg[i] = *(const short8_t*)(Kbase + ((size_t)64 + (idx >> 5)) * 256 + (idx & 31) * 8);
                vreg[i] = *(const short8_t*)(Vbase + (size_t)(idx >> 3) * 4096 + 64 + (idx & 7) * 8);
            }
        }

        for (int kb = 0; kb <= w; kb++){
            const int cb = kb & 1;
            __syncthreads();   // B1: tile kb visible in Ks/Vs[cb]; Ks/Vs[cb^1] free (prev PV done); Pls WAR
            if (kb < w){
                #pragma unroll
                for (int i = 0; i < 4; i++){
                    int idx = tid + i * 512;
                    *(short8_t*)&Ks[cb ^ 1][(idx >> 5) * 264 + (idx & 31) * 8] = kreg[i];
                    *(short8_t*)&Vs[cb ^ 1][(idx >> 3) * 72  + (idx & 7)  * 8] = vreg[i];
                }
                if (kb + 1 < w){
                    const short* ksrc = Kbase + ((size_t)(kb + 2) * 64) * 256;
                    const short* vsrc = Vbase + (size_t)(kb + 2) * 64;
                    #pragma unroll
                    for (int i = 0; i < 4; i++){
                        int idx = tid + i * 512;
                        kreg[i] = *(const short8_t*)(ksrc + (size_t)(idx >> 5) * 256 + (idx & 31) * 8);
                        vreg[i] = *(const short8_t*)(vsrc + (size_t)(idx >> 3) * 4096 + (idx & 7) * 8);
                    }
                }
            }

            // QK: one 16x16 S tile per wave, from Ks[cb]
            f32x4 s0 = {};
            #pragma unroll
            for (int ks = 0; ks < 8; ks++){
                short8_t bf = *(short8_t*)&Ks[cb][(kc * 16 + l15) * 264 + ks * 32 + lq * 8];
                s0 = mfma16(qf[ks], bf, s0);
            }
            #pragma unroll
            for (int r = 0; r < 4; r++) s0[r] *= 0.0625f;

            // per-wave row max (16 lanes) on VALU via DPP
            f32x4 mx = s0;
            rowred_max(mx);
            if (l15 == 0){
                #pragma unroll
                for (int r = 0; r < 4; r++) pmaxs[(rg2 * 16 + lq * 4 + r) * 4 + kc] = mx[r];
            }
            __syncthreads();   // B2: pmaxs ready

            // replicated stats update (regs only), exp, P write
            f32x4 p;
            #pragma unroll
            for (int r = 0; r < 4; r++){
                int row = rg2 * 16 + lq * 4 + r;
                f32x4 pm4 = *(const f32x4*)&pmaxs[row * 4];
                float pm = fmaxf(fmaxf(pm4[0], pm4[1]), fmaxf(pm4[2], pm4[3]));
                float mn = fmaxf(m_reg[r], pm);
                al_reg[r] = exp2f((m_reg[r] - mn) * LOG2E);
                m_reg[r] = mn;
                p[r] = exp2f((s0[r] - mn) * LOG2E);
            }
            #pragma unroll
            for (int r = 0; r < 4; r++)
                Pls[(rg2 * 16 + lq * 4 + r) * 72 + kc * 16 + l15] = f2bf(p[r]);
            f32x4 sm = p;
            rowred_sum(sm);
            #pragma unroll
            for (int r = 0; r < 4; r++){
                l_reg[r] = l_reg[r] * al_reg[r] + sm[r];   // per-kc partial l
                #pragma unroll
                for (int nt = 0; nt < 4; nt++) oacc[nt][r] *= al_reg[r];
            }
            __syncthreads();   // B3: Pls ready

            // PV from Vs[cb]: wave owns channels kc*64 .. kc*64+64
            #pragma unroll
            for (int kk = 0; kk < 2; kk++){
                short8_t a = *(short8_t*)&Pls[(rg2 * 16 + l15) * 72 + kk * 32 + lq * 8];
                #pragma unroll
                for (int nt = 0; nt < 4; nt++){
                    short8_t bfr = *(short8_t*)&Vs[cb][(kc * 64 + nt * 16 + l15) * 72 + kk * 32 + lq * 8];
                    oacc[nt] = mfma16(a, bfr, oacc[nt]);
                }
            }
        }

        // epilogue: combine per-kc l partials, O /= l, write back in n = h*64 + w order
        __syncthreads();       // last PV done; pmaxs free for reuse as l exchange
        if (l15 == 0){
            #pragma unroll
            for (int r = 0; r < 4; r++) pmaxs[(rg2 * 16 + lq * 4 + r) * 4 + kc] = l_reg[r];
        }
        __syncthreads();
        #pragma unroll
        for (int r = 0; r < 4; r++){
            int row = rg2 * 16 + lq * 4 + r;
            f32x4 l4 = *(const f32x4*)&pmaxs[row * 4];
            float inv = 1.f / (l4[0] + l4[1] + l4[2] + l4[3]);
            int h = hh * 32 + row;
            size_t base = ((size_t)b * 4096 + h * 64 + w) * 256;
            #pragma unroll
            for (int nt = 0; nt < 4; nt++)
                hb[base + kc * 64 + nt * 16 + l15] = f2bf(oacc[nt][r] * inv);
        }
        __syncthreads();       // before next segment overwrites Ks/Vs/pmaxs
    }
}

// ---------- K5: final proj + bias + residual, coalesced f32 store to (B,C,H,W) ----------
__global__ __launch_bounds__(256) void final_gemm(const short* __restrict__ hbuf,
    const short* __restrict__ wT3, const float* __restrict__ b3,
    const float* __restrict__ x, float* __restrict__ out)
{
    __shared__ short As[64 * 72];
    __shared__ short Bs[64 * 72];
    __shared__ float CT[64 * 65];

    const int tid = threadIdx.x;
    const int m0 = blockIdx.x * 64;        // 64 consecutive n -> fixed h, w = 0..63
    const int d0 = blockIdx.y * 64;
    const int wv = tid >> 6, lane = tid & 63;
    const int wrow = (wv >> 1) * 32, wcol = (wv & 1) * 32;
    const int lrow = lane & 15, lq = lane >> 4;

    f32x4 acc[2][2] = {};
    for (int k0 = 0; k0 < 256; k0 += 64){
        __syncthreads();
        #pragma unroll
        for (int i = 0; i < 2; i++){
            int idx = tid + i * 256, r = idx >> 3, c = (idx & 7) * 8;
            *(short8_t*)&As[r * 72 + c] = *(const short8_t*)(hbuf + (size_t)(m0 + r) * 256 + k0 + c);
            *(short8_t*)&Bs[r * 72 + c] = *(const short8_t*)(wT3 + (size_t)(d0 + r) * 256 + k0 + c);
        }
        __syncthreads();
        #pragma unroll
        for (int kk = 0; kk < 2; kk++){
            int off = kk * 32 + lq * 8;
            short8_t a0  = *(short8_t*)&As[(wrow + lrow) * 72 + off];
            short8_t a1  = *(short8_t*)&As[(wrow + 16 + lrow) * 72 + off];
            short8_t b0v = *(short8_t*)&Bs[(wcol + lrow) * 72 + off];
            short8_t b1v = *(short8_t*)&Bs[(wcol + 16 + lrow) * 72 + off];
            acc[0][0] = mfma16(a0, b0v, acc[0][0]);
            acc[0][1] = mfma16(a0, b1v, acc[0][1]);
            acc[1][0] = mfma16(a1, b0v, acc[1][0]);
            acc[1][1] = mfma16(a1, b1v, acc[1][1]);
        }
    }
    #pragma unroll
    for (int i = 0; i < 2; i++)
      #pragma unroll
      for (int j = 0; j < 2; j++)
        #pragma unroll
        for (int r = 0; r < 4; r++){
            int row = wrow + i * 16 + lq * 4 + r;
            int col = wcol + j * 16 + lrow;
            CT[col * 65 + row] = acc[i][j][r] + b3[d0 + col];
        }
    __syncthreads();
    int b = m0 >> 12, n0 = m0 & 4095, hrow = n0 >> 6;
    int dr = tid >> 2, wc = (tid & 3) * 16;
    size_t base = ((size_t)(b * 256 + d0 + dr) * 64 + hrow) * 64 + wc;
    const f32x4* xp = (const f32x4*)(x + base);
    f32x4* op = (f32x4*)(out + base);
    #pragma unroll
    for (int q = 0; q < 4; q++){
        f32x4 xv = xp[q], o;
        #pragma unroll
        for (int j = 0; j < 4; j++) o[j] = xv[j] + CT[dr * 65 + wc + q * 4 + j];
        op[q] = o;
    }
}

extern "C" void kernel_launch(void* const* d_in, const int* in_sizes, int n_in,
                              void* d_out, int out_size, void* d_ws, size_t ws_size,
                              hipStream_t stream)
{
    const float* x   = (const float*)d_in[0];
    const float* gnw = (const float*)d_in[1];
    const float* gnb = (const float*)d_in[2];
    const float* w0  = (const float*)d_in[3];
    const float* b0  = (const float*)d_in[4];
    const float* w1  = (const float*)d_in[5];
    const float* b1  = (const float*)d_in[6];
    const float* w2  = (const float*)d_in[7];
    const float* b2  = (const float*)d_in[8];
    const float* w3  = (const float*)d_in[9];
    const float* b3  = (const float*)d_in[10];
    float* out = (float*)d_out;

    char* ws = (char*)d_ws;
    short* wT  = (short*)(ws);                  // 4 * 256*256 bf16  = 512 KB
    short* hn  = (short*)(ws + 524288);         // (B, m~, C) bf16   = 8 MB
    short* Qb  = (short*)(ws + 8912896);        // 8 MB
    short* Kb  = (short*)(ws + 17301504);       // 8 MB
    short* Vt  = (short*)(ws + 25690112);       // (B, C, m~) 8 MB
    short* hb  = (short*)(ws + 34078720);       // (B, n, C)  8 MB   (end 40.5 MB)

    prep_w   <<<1024, 256, 0, stream>>>(w0, w1, w2, w3, wT);
    gn_kernel<<<2048, 256, 0, stream>>>(x, gnw, gnb, hn);
    qkv_gemm <<<dim3(256, 12), 256, 0, stream>>>(hn, wT, b0, b1, b2, Qb, Kb, Vt);
    attn_kernel<<<dim3(64, 4), 512, 0, stream>>>(Qb, Kb, Vt, hb);
    final_gemm<<<dim3(256, 4), 256, 0, stream>>>(hb, wT + 3 * 65536, b3, x, out);
}